// Round 2
// baseline (245.469 us; speedup 1.0000x reference)
//
#include <hip/hip_runtime.h>
#include <hip/hip_bf16.h>

#define B_  8
#define T_  2048
#define E_  1024
#define H_  64
#define BT_ (B_*T_)

typedef __attribute__((ext_vector_type(8))) __bf16 bf16x8;
typedef __attribute__((ext_vector_type(4))) float  f32x4;

__device__ __forceinline__ unsigned short f2bfu(float f) {
    union { float f; unsigned u; } v; v.f = f;
    unsigned r = v.u + 0x7fffu + ((v.u >> 16) & 1u);
    return (unsigned short)(r >> 16);
}

// ---------------- Phase 0: W [E,H] fp32 -> wtb [3][H][E] bf16 (transposed) ----
// Grid 192 blocks (mat*64 + h), 256 threads; thread handles 4 e's.
__global__ __launch_bounds__(256)
void wprep_kernel(const float* __restrict__ Wq,
                  const float* __restrict__ Wk,
                  const float* __restrict__ Wv,
                  unsigned short* __restrict__ wtb)
{
    const int mat = blockIdx.x >> 6;
    const int h   = blockIdx.x & 63;
    const float* W = (mat == 0) ? Wq : (mat == 1 ? Wk : Wv);
    unsigned short* row = wtb + ((long)(mat * 64 + h)) * E_;
    const int e0 = threadIdx.x * 4;
    unsigned p0 = f2bfu(W[(e0 + 0) * H_ + h]) | ((unsigned)f2bfu(W[(e0 + 1) * H_ + h]) << 16);
    unsigned p1 = f2bfu(W[(e0 + 2) * H_ + h]) | ((unsigned)f2bfu(W[(e0 + 3) * H_ + h]) << 16);
    *(uint2*)&row[e0] = (uint2){p0, p1};
}

// ---------------- Phase 1: QKV projection ----------------
// Block = 16 tokens, 256 threads (4 waves). Wave w owns h-tile w (cols w*16..).
// x staged in LDS (bf16, double-buffered, 1 barrier/iter); W^T read from global.
__global__ __launch_bounds__(256, 4)
void qkv_kernel(const float* __restrict__ x,
                const unsigned short* __restrict__ wtb,
                unsigned short* __restrict__ qb,
                unsigned short* __restrict__ kb,
                unsigned short* __restrict__ vtb)
{
    __shared__ unsigned short xs[2][16 * 72];   // 16 rows x 64 k, stride 72

    const int tid  = threadIdx.x;
    const int wave = tid >> 6;
    const int lane = tid & 63;
    const int quad = lane >> 4;
    const int col  = lane & 15;
    const long r0  = (long)blockIdx.x * 16;

    f32x4 acc[3];
#pragma unroll
    for (int m = 0; m < 3; ++m) acc[m] = (f32x4){0.f, 0.f, 0.f, 0.f};

    const int xrow = tid >> 4;            // 0..15
    const int xkc  = (tid & 15) * 4;      // 0,4,...,60
    const float* xbase = x + (r0 + xrow) * E_ + xkc;

    float4 xv = *(const float4*)xbase;    // prefetch chunk 0

    for (int k0 = 0, it = 0; k0 < E_; k0 += 64, ++it) {
        unsigned p0 = f2bfu(xv.x) | ((unsigned)f2bfu(xv.y) << 16);
        unsigned p1 = f2bfu(xv.z) | ((unsigned)f2bfu(xv.w) << 16);
        *(uint2*)&xs[it & 1][xrow * 72 + xkc] = (uint2){p0, p1};
        __syncthreads();
        if (k0 + 64 < E_) xv = *(const float4*)(xbase + k0 + 64);   // prefetch next

#pragma unroll
        for (int ks = 0; ks < 2; ++ks) {
            bf16x8 af = *(const bf16x8*)&xs[it & 1][col * 72 + ks * 32 + quad * 8];
            const int kk = k0 + ks * 32 + quad * 8;
#pragma unroll
            for (int m = 0; m < 3; ++m) {
                bf16x8 bfg = *(const bf16x8*)&wtb[((long)(m * 64 + wave * 16 + col)) * E_ + kk];
                acc[m] = __builtin_amdgcn_mfma_f32_16x16x32_bf16(af, bfg, acc[m], 0, 0, 0);
            }
        }
    }

    // epilogue: C/D layout col=lane&15, row=quad*4+reg; h = wave*16+col
    const int bidx = (int)(r0 >> 11);
    const int h    = wave * 16 + col;
#pragma unroll
    for (int r = 0; r < 4; ++r) {
        long t = r0 + quad * 4 + r;
        qb[t * H_ + h] = f2bfu(acc[0][r] * 0.125f);    // fold 1/sqrt(H)
        kb[t * H_ + h] = f2bfu(acc[1][r]);
        vtb[((long)(bidx * H_ + h)) * T_ + (t & (T_ - 1))] = f2bfu(acc[2][r]);
    }
}

// ---------------- Phase 2: causal flash attention ----------------
// Block = (batch, 32-row q-tile), 128 threads (2 waves), key tiles of 64.
#define TS 72

__global__ __launch_bounds__(128, 4)
void attn_kernel(const unsigned short* __restrict__ qb,
                 const unsigned short* __restrict__ kb,
                 const unsigned short* __restrict__ vtb,
                 float* __restrict__ out)
{
    __shared__ unsigned short qs[32 * TS];
    __shared__ unsigned short ks[64 * TS];
    __shared__ unsigned short vs[64 * TS];      // [h][t]
    __shared__ unsigned short ps[2][16 * TS];   // per-wave P scratch

    const int tid  = threadIdx.x;
    const int wave = tid >> 6;
    const int lane = tid & 63;
    const int quad = lane >> 4;
    const int col  = lane & 15;
    const int qt   = blockIdx.x & 63;
    const int b    = blockIdx.x >> 6;

    // stage Q tile (32x64 bf16): 256 uint4, 2 per thread
    {
        const uint4* src = (const uint4*)(qb + ((long)b * T_ + qt * 32) * H_);
#pragma unroll
        for (int i = 0; i < 2; ++i) {
            int idx = tid + i * 128;
            int row = idx >> 3, c = idx & 7;
            *(uint4*)&qs[row * TS + c * 8] = src[idx];
        }
    }

    f32x4 o[4];
    float m_i[4], l_i[4];
#pragma unroll
    for (int n = 0; n < 4; ++n) o[n] = (f32x4){0.f, 0.f, 0.f, 0.f};
#pragma unroll
    for (int r = 0; r < 4; ++r) { m_i[r] = -1e30f; l_i[r] = 0.f; }

    const int nt = (qt >> 1) + 1;
    for (int s = 0; s < nt; ++s) {
        // stage K tile [64 keys][64 h] and V^T tile [64 h][64 keys]: 4 uint4 each
        {
            const uint4* ksrc = (const uint4*)(kb + ((long)b * T_ + s * 64) * H_);
#pragma unroll
            for (int i = 0; i < 4; ++i) {
                int idx = tid + i * 128;
                int row = idx >> 3, c = idx & 7;
                *(uint4*)&ks[row * TS + c * 8] = ksrc[idx];
                const uint4* vsrc =
                    (const uint4*)(vtb + ((long)(b * H_ + row)) * T_ + s * 64) + c;
                *(uint4*)&vs[row * TS + c * 8] = *vsrc;
            }
        }
        __syncthreads();

        // S = Q K^T
        bf16x8 qa0 = *(const bf16x8*)&qs[(wave * 16 + col) * TS + quad * 8];
        bf16x8 qa1 = *(const bf16x8*)&qs[(wave * 16 + col) * TS + quad * 8 + 32];
        f32x4 sa[4];
#pragma unroll
        for (int kt = 0; kt < 4; ++kt) {
            bf16x8 kf0 = *(const bf16x8*)&ks[(kt * 16 + col) * TS + quad * 8];
            bf16x8 kf1 = *(const bf16x8*)&ks[(kt * 16 + col) * TS + quad * 8 + 32];
            sa[kt] = (f32x4){0.f, 0.f, 0.f, 0.f};
            sa[kt] = __builtin_amdgcn_mfma_f32_16x16x32_bf16(qa0, kf0, sa[kt], 0, 0, 0);
            sa[kt] = __builtin_amdgcn_mfma_f32_16x16x32_bf16(qa1, kf1, sa[kt], 0, 0, 0);
        }

        // causal mask (only the last tile can cross the diagonal)
        if (s == nt - 1) {
#pragma unroll
            for (int kt = 0; kt < 4; ++kt) {
                int kg = s * 64 + kt * 16 + col;
#pragma unroll
                for (int r = 0; r < 4; ++r) {
                    int qg = qt * 32 + wave * 16 + quad * 4 + r;
                    if (kg > qg) sa[kt][r] = -1e30f;
                }
            }
        }

        // online softmax
        float mx[4];
#pragma unroll
        for (int r = 0; r < 4; ++r)
            mx[r] = fmaxf(fmaxf(sa[0][r], sa[1][r]), fmaxf(sa[2][r], sa[3][r]));
#pragma unroll
        for (int off = 1; off < 16; off <<= 1)
#pragma unroll
            for (int r = 0; r < 4; ++r)
                mx[r] = fmaxf(mx[r], __shfl_xor(mx[r], off, 64));

        float alpha[4], mnew[4];
#pragma unroll
        for (int r = 0; r < 4; ++r) {
            mnew[r]  = fmaxf(m_i[r], mx[r]);
            alpha[r] = __builtin_amdgcn_exp2f((m_i[r] - mnew[r]) * 1.44269504f);
            m_i[r]   = mnew[r];
        }

        float rs[4] = {0.f, 0.f, 0.f, 0.f};
#pragma unroll
        for (int kt = 0; kt < 4; ++kt)
#pragma unroll
            for (int r = 0; r < 4; ++r) {
                float p = __builtin_amdgcn_exp2f((sa[kt][r] - mnew[r]) * 1.44269504f);
                rs[r] += p;
                ps[wave][(quad * 4 + r) * TS + kt * 16 + col] = f2bfu(p);
            }
#pragma unroll
        for (int off = 1; off < 16; off <<= 1)
#pragma unroll
            for (int r = 0; r < 4; ++r)
                rs[r] += __shfl_xor(rs[r], off, 64);
#pragma unroll
        for (int r = 0; r < 4; ++r)
            l_i[r] = l_i[r] * alpha[r] + rs[r];

#pragma unroll
        for (int n = 0; n < 4; ++n)
#pragma unroll
            for (int r = 0; r < 4; ++r)
                o[n][r] *= alpha[r];

        bf16x8 pa0 = *(const bf16x8*)&ps[wave][col * TS + quad * 8];
        bf16x8 pa1 = *(const bf16x8*)&ps[wave][col * TS + quad * 8 + 32];
#pragma unroll
        for (int n = 0; n < 4; ++n) {
            bf16x8 vf0 = *(const bf16x8*)&vs[(n * 16 + col) * TS + quad * 8];
            bf16x8 vf1 = *(const bf16x8*)&vs[(n * 16 + col) * TS + quad * 8 + 32];
            o[n] = __builtin_amdgcn_mfma_f32_16x16x32_bf16(pa0, vf0, o[n], 0, 0, 0);
            o[n] = __builtin_amdgcn_mfma_f32_16x16x32_bf16(pa1, vf1, o[n], 0, 0, 0);
        }
        __syncthreads();
    }

    // epilogue
#pragma unroll
    for (int r = 0; r < 4; ++r) {
        float inv = 1.0f / l_i[r];
        long row = (long)b * T_ + qt * 32 + wave * 16 + quad * 4 + r;
#pragma unroll
        for (int n = 0; n < 4; ++n)
            out[row * H_ + n * 16 + col] = o[n][r] * inv;
    }
}

extern "C" void kernel_launch(void* const* d_in, const int* in_sizes, int n_in,
                              void* d_out, int out_size, void* d_ws, size_t ws_size,
                              hipStream_t stream) {
    (void)in_sizes; (void)n_in; (void)out_size; (void)ws_size;
    const float* x  = (const float*)d_in[0];
    const float* Wq = (const float*)d_in[1];
    const float* Wk = (const float*)d_in[2];
    const float* Wv = (const float*)d_in[3];

    unsigned short* qb  = (unsigned short*)d_ws;               // 2 MB
    unsigned short* kb  = qb + (size_t)BT_ * H_;               // 2 MB
    unsigned short* vtb = kb + (size_t)BT_ * H_;               // 2 MB
    unsigned short* wtb = vtb + (size_t)BT_ * H_;              // 384 KB

    wprep_kernel<<<192, 256, 0, stream>>>(Wq, Wk, Wv, wtb);
    qkv_kernel<<<BT_ / 16, 256, 0, stream>>>(x, wtb, qb, kb, vtb);
    attn_kernel<<<B_ * (T_ / 32), 128, 0, stream>>>(qb, kb, vtb, (float*)d_out);
}

// Round 3
// 179.620 us; speedup vs baseline: 1.3666x; 1.3666x over previous
//
#include <hip/hip_runtime.h>
#include <hip/hip_bf16.h>

#define B_  8
#define T_  2048
#define E_  1024
#define H_  64
#define BT_ (B_*T_)

typedef __attribute__((ext_vector_type(8))) __bf16 bf16x8;
typedef __attribute__((ext_vector_type(4))) float  f32x4;

__device__ __forceinline__ unsigned short f2bfu(float f) {
    union { float f; unsigned u; } v; v.f = f;
    unsigned r = v.u + 0x7fffu + ((v.u >> 16) & 1u);
    return (unsigned short)(r >> 16);
}

// Q pre-scale: 1/sqrt(H) * log2(e)  (attn softmax runs in exp2 domain)
#define QSCALE (0.125f * 1.44269504f)

// ---------------- Phase 0: W -> fragment-major swizzled W^T (bf16) ----------
// wf layout: [c(32 k-chunks)][m(3)][n(4 h-tiles)][lane(64)][j(8)]
// element = W_m[k = c*32 + (lane>>4)*8 + j][h = n*16 + (lane&15)]
// => qkv's B-fragment load is 64 lanes x contiguous 16B = one coalesced 1KB load.
__global__ __launch_bounds__(256)
void wprep_kernel(const float* __restrict__ Wq,
                  const float* __restrict__ Wk,
                  const float* __restrict__ Wv,
                  unsigned short* __restrict__ wf)
{
    const int c = blockIdx.x / 3;
    const int m = blockIdx.x % 3;
    const float* W = (m == 0) ? Wq : (m == 1 ? Wk : Wv);
    const float scale = (m == 0) ? QSCALE : 1.0f;

    const int n    = threadIdx.x >> 6;
    const int lane = threadIdx.x & 63;
    const int quad = lane >> 4;
    const int col  = lane & 15;
    const int h    = n * 16 + col;

    unsigned short tmp[8];
#pragma unroll
    for (int j = 0; j < 8; ++j)
        tmp[j] = f2bfu(W[(c * 32 + quad * 8 + j) * H_ + h] * scale);
    *(uint4*)&wf[(((c * 3 + m) * 4 + n) * 64 + lane) * 8] = *(uint4*)tmp;
}

// ---------------- Phase 1: QKV projection ----------------
// Block = 16 tokens, 4 waves; wave w owns h-tile w for all 3 matrices.
// x staged in LDS (bf16, double-buffered); W read as coalesced fragments.
__global__ __launch_bounds__(256, 4)
void qkv_kernel(const float* __restrict__ x,
                const unsigned short* __restrict__ wf,
                unsigned short* __restrict__ qb,
                unsigned short* __restrict__ kb,
                unsigned short* __restrict__ vtb)
{
    __shared__ unsigned short xs[2][16 * 72];

    const int tid  = threadIdx.x;
    const int wave = tid >> 6;
    const int lane = tid & 63;
    const int quad = lane >> 4;
    const int col  = lane & 15;
    const long r0  = (long)blockIdx.x * 16;

    f32x4 acc[3];
#pragma unroll
    for (int m = 0; m < 3; ++m) acc[m] = (f32x4){0.f, 0.f, 0.f, 0.f};

    const int xrow = tid >> 4;
    const int xkc  = (tid & 15) * 4;
    const float* xbase = x + (r0 + xrow) * E_ + xkc;

    float4 xv = *(const float4*)xbase;

    for (int k0 = 0, it = 0; k0 < E_; k0 += 64, ++it) {
        unsigned p0 = f2bfu(xv.x) | ((unsigned)f2bfu(xv.y) << 16);
        unsigned p1 = f2bfu(xv.z) | ((unsigned)f2bfu(xv.w) << 16);
        *(uint2*)&xs[it & 1][xrow * 72 + xkc] = (uint2){p0, p1};
        __syncthreads();
        if (k0 + 64 < E_) xv = *(const float4*)(xbase + k0 + 64);

#pragma unroll
        for (int ks = 0; ks < 2; ++ks) {
            const int c = it * 2 + ks;
            bf16x8 af = *(const bf16x8*)&xs[it & 1][col * 72 + ks * 32 + quad * 8];
#pragma unroll
            for (int m = 0; m < 3; ++m) {
                bf16x8 bfg = *(const bf16x8*)&wf[(((c * 3 + m) * 4 + wave) * 64 + lane) * 8];
                acc[m] = __builtin_amdgcn_mfma_f32_16x16x32_bf16(af, bfg, acc[m], 0, 0, 0);
            }
        }
    }

    const int bidx = (int)(r0 >> 11);
    const int h    = wave * 16 + col;
#pragma unroll
    for (int r = 0; r < 4; ++r) {
        long t = r0 + quad * 4 + r;
        qb[t * H_ + h] = f2bfu(acc[0][r]);        // scale folded into Wq
        kb[t * H_ + h] = f2bfu(acc[1][r]);
        vtb[((long)(bidx * H_ + h)) * T_ + (t & (T_ - 1))] = f2bfu(acc[2][r]);
    }
}

// ---------------- Phase 2: balanced causal flash attention ----------------
// Block = (batch, pair p): q-tiles p and 63-p (32 rows each), sequential.
// 4 waves = 2 split-K groups x 2 waves (16 q-rows each); group g takes
// key-tiles s = g, g+2, ... Every block runs exactly 17 lockstep iterations.
#define TS 72

__global__ __launch_bounds__(256, 2)
void attn_kernel(const unsigned short* __restrict__ qb,
                 const unsigned short* __restrict__ kb,
                 const unsigned short* __restrict__ vtb,
                 float* __restrict__ out)
{
    __shared__ unsigned short qs[32 * TS];          // 4.6 KB
    __shared__ unsigned short ks[2][64 * TS];       // 9.2 KB per group
    __shared__ unsigned short vs[2][64 * TS];       // [h][t]
    __shared__ unsigned short ps[4][16 * TS];       // per-wave P scratch (9.2 KB)
    __shared__ float mcomb[2][16], lcomb[2][16];
    float* ocomb = (float*)ps;                      // overlay: [gw][16][68] f32 (8.7 KB)

    const int tid  = threadIdx.x;
    const int wave = tid >> 6;
    const int lane = tid & 63;
    const int quad = lane >> 4;
    const int col  = lane & 15;
    const int grp  = wave >> 1;       // split-K group
    const int gw   = wave & 1;        // wave-in-group -> q-rows gw*16..
    const int lt   = tid & 127;       // thread-in-group (for staging)
    const int b    = blockIdx.x >> 5;
    const int p    = blockIdx.x & 31;

    for (int half = 0; half < 2; ++half) {
        const int qt = half ? (63 - p) : p;
        const int nt = (qt >> 1) + 1;
        const int iters = (nt + 1) >> 1;

        // stage Q tile (32x64 bf16 = 256 uint4, 1 per thread)
        {
            const uint4* src = (const uint4*)(qb + ((long)b * T_ + qt * 32) * H_);
            int row = tid >> 3, c = tid & 7;
            *(uint4*)&qs[row * TS + c * 8] = src[tid];
        }

        f32x4 o[4];
        float m_i[4], l_i[4];
#pragma unroll
        for (int n = 0; n < 4; ++n) o[n] = (f32x4){0.f, 0.f, 0.f, 0.f};
#pragma unroll
        for (int r = 0; r < 4; ++r) { m_i[r] = -1e30f; l_i[r] = 0.f; }

        // register prefetch of this group's first tile
        uint4 kreg[4], vreg[4];
        {
            int s = grp;
            if (s < nt) {
                const uint4* ksrc = (const uint4*)(kb + ((long)b * T_ + s * 64) * H_);
#pragma unroll
                for (int i = 0; i < 4; ++i) {
                    int idx = lt + i * 128;
                    int row = idx >> 3, c = idx & 7;
                    kreg[i] = ksrc[idx];
                    vreg[i] = *((const uint4*)(vtb + ((long)(b * H_ + row)) * T_ + s * 64) + c);
                }
            }
        }

        for (int it = 0; it < iters; ++it) {
            const int s = grp + it * 2;
            const bool active = (s < nt);

            __syncthreads();            // previous compute done reading ks/vs
            if (active) {
#pragma unroll
                for (int i = 0; i < 4; ++i) {
                    int idx = lt + i * 128;
                    int row = idx >> 3, c = idx & 7;
                    *(uint4*)&ks[grp][row * TS + c * 8] = kreg[i];
                    *(uint4*)&vs[grp][row * TS + c * 8] = vreg[i];
                }
            }
            __syncthreads();

            // prefetch next tile for this group (overlaps compute below)
            const int s2 = s + 2;
            if (s2 < nt) {
                const uint4* ksrc = (const uint4*)(kb + ((long)b * T_ + s2 * 64) * H_);
#pragma unroll
                for (int i = 0; i < 4; ++i) {
                    int idx = lt + i * 128;
                    int row = idx >> 3, c = idx & 7;
                    kreg[i] = ksrc[idx];
                    vreg[i] = *((const uint4*)(vtb + ((long)(b * H_ + row)) * T_ + s2 * 64) + c);
                }
            }

            if (active) {
                // S = Q K^T  (sa already in exp2 units; scale folded into Wq)
                bf16x8 qa0 = *(const bf16x8*)&qs[(gw * 16 + col) * TS + quad * 8];
                bf16x8 qa1 = *(const bf16x8*)&qs[(gw * 16 + col) * TS + quad * 8 + 32];
                f32x4 sa[4];
#pragma unroll
                for (int kt = 0; kt < 4; ++kt) {
                    bf16x8 kf0 = *(const bf16x8*)&ks[grp][(kt * 16 + col) * TS + quad * 8];
                    bf16x8 kf1 = *(const bf16x8*)&ks[grp][(kt * 16 + col) * TS + quad * 8 + 32];
                    sa[kt] = (f32x4){0.f, 0.f, 0.f, 0.f};
                    sa[kt] = __builtin_amdgcn_mfma_f32_16x16x32_bf16(qa0, kf0, sa[kt], 0, 0, 0);
                    sa[kt] = __builtin_amdgcn_mfma_f32_16x16x32_bf16(qa1, kf1, sa[kt], 0, 0, 0);
                }

                if (s == nt - 1) {       // diagonal tile
#pragma unroll
                    for (int kt = 0; kt < 4; ++kt) {
                        int kg = s * 64 + kt * 16 + col;
#pragma unroll
                        for (int r = 0; r < 4; ++r) {
                            int qg = qt * 32 + gw * 16 + quad * 4 + r;
                            if (kg > qg) sa[kt][r] = -1e30f;
                        }
                    }
                }

                float mx[4];
#pragma unroll
                for (int r = 0; r < 4; ++r)
                    mx[r] = fmaxf(fmaxf(sa[0][r], sa[1][r]), fmaxf(sa[2][r], sa[3][r]));
#pragma unroll
                for (int off = 1; off < 16; off <<= 1)
#pragma unroll
                    for (int r = 0; r < 4; ++r)
                        mx[r] = fmaxf(mx[r], __shfl_xor(mx[r], off, 64));

                float alpha[4], mnew[4];
#pragma unroll
                for (int r = 0; r < 4; ++r) {
                    mnew[r]  = fmaxf(m_i[r], mx[r]);
                    alpha[r] = __builtin_amdgcn_exp2f(m_i[r] - mnew[r]);
                    m_i[r]   = mnew[r];
                }

                float rs[4] = {0.f, 0.f, 0.f, 0.f};
#pragma unroll
                for (int kt = 0; kt < 4; ++kt)
#pragma unroll
                    for (int r = 0; r < 4; ++r) {
                        float pv = __builtin_amdgcn_exp2f(sa[kt][r] - mnew[r]);
                        rs[r] += pv;
                        ps[wave][(quad * 4 + r) * TS + kt * 16 + col] = f2bfu(pv);
                    }
#pragma unroll
                for (int off = 1; off < 16; off <<= 1)
#pragma unroll
                    for (int r = 0; r < 4; ++r)
                        rs[r] += __shfl_xor(rs[r], off, 64);
#pragma unroll
                for (int r = 0; r < 4; ++r)
                    l_i[r] = l_i[r] * alpha[r] + rs[r];

#pragma unroll
                for (int n = 0; n < 4; ++n)
#pragma unroll
                    for (int r = 0; r < 4; ++r)
                        o[n][r] *= alpha[r];

                bf16x8 pa0 = *(const bf16x8*)&ps[wave][col * TS + quad * 8];
                bf16x8 pa1 = *(const bf16x8*)&ps[wave][col * TS + quad * 8 + 32];
#pragma unroll
                for (int n = 0; n < 4; ++n) {
                    bf16x8 vf0 = *(const bf16x8*)&vs[grp][(n * 16 + col) * TS + quad * 8];
                    bf16x8 vf1 = *(const bf16x8*)&vs[grp][(n * 16 + col) * TS + quad * 8 + 32];
                    o[n] = __builtin_amdgcn_mfma_f32_16x16x32_bf16(pa0, vf0, o[n], 0, 0, 0);
                    o[n] = __builtin_amdgcn_mfma_f32_16x16x32_bf16(pa1, vf1, o[n], 0, 0, 0);
                }
            }
        }

        // ---- split-K combine: group 1 publishes, group 0 merges & stores ----
        __syncthreads();                 // all compute done; ps reusable as ocomb
        if (grp == 1) {
#pragma unroll
            for (int r = 0; r < 4; ++r) {
#pragma unroll
                for (int n = 0; n < 4; ++n)
                    ocomb[(gw * 16 + quad * 4 + r) * 68 + n * 16 + col] = o[n][r];
                if (col == 0 && quad == 0) {}   // no-op; keep lanes uniform
            }
            if (col == 0) {
#pragma unroll
                for (int r = 0; r < 4; ++r) {
                    mcomb[gw][quad * 4 + r] = m_i[r];
                    lcomb[gw][quad * 4 + r] = l_i[r];
                }
            }
        }
        __syncthreads();
        if (grp == 0) {
#pragma unroll
            for (int r = 0; r < 4; ++r) {
                float m1 = mcomb[gw][quad * 4 + r];
                float l1 = lcomb[gw][quad * 4 + r];
                float mm = fmaxf(m_i[r], m1);
                float a0 = __builtin_amdgcn_exp2f(m_i[r] - mm);
                float a1 = __builtin_amdgcn_exp2f(m1 - mm);
                float inv = 1.0f / (l_i[r] * a0 + l1 * a1);
                long row = (long)b * T_ + qt * 32 + gw * 16 + quad * 4 + r;
#pragma unroll
                for (int n = 0; n < 4; ++n) {
                    float o1 = ocomb[(gw * 16 + quad * 4 + r) * 68 + n * 16 + col];
                    out[row * H_ + n * 16 + col] = (o[n][r] * a0 + o1 * a1) * inv;
                }
            }
        }
        __syncthreads();                 // before next half reuses qs/ps
    }
}

extern "C" void kernel_launch(void* const* d_in, const int* in_sizes, int n_in,
                              void* d_out, int out_size, void* d_ws, size_t ws_size,
                              hipStream_t stream) {
    (void)in_sizes; (void)n_in; (void)out_size; (void)ws_size;
    const float* x  = (const float*)d_in[0];
    const float* Wq = (const float*)d_in[1];
    const float* Wk = (const float*)d_in[2];
    const float* Wv = (const float*)d_in[3];

    unsigned short* qb  = (unsigned short*)d_ws;               // 2 MB
    unsigned short* kb  = qb + (size_t)BT_ * H_;               // 2 MB
    unsigned short* vtb = kb + (size_t)BT_ * H_;               // 2 MB
    unsigned short* wf  = vtb + (size_t)BT_ * H_;              // 384 KB

    wprep_kernel<<<96, 256, 0, stream>>>(Wq, Wk, Wv, wf);
    qkv_kernel<<<BT_ / 16, 256, 0, stream>>>(x, wf, qb, kb, vtb);
    attn_kernel<<<B_ * 32, 256, 0, stream>>>(qb, kb, vtb, (float*)d_out);
}

// Round 4
// 170.916 us; speedup vs baseline: 1.4362x; 1.0509x over previous
//
#include <hip/hip_runtime.h>
#include <hip/hip_bf16.h>

#define B_  8
#define T_  2048
#define E_  1024
#define H_  64
#define BT_ (B_*T_)

typedef __attribute__((ext_vector_type(8))) __bf16 bf16x8;
typedef __attribute__((ext_vector_type(4))) float  f32x4;

__device__ __forceinline__ unsigned short f2bfu(float f) {
    union { float f; unsigned u; } v; v.f = f;
    unsigned r = v.u + 0x7fffu + ((v.u >> 16) & 1u);
    return (unsigned short)(r >> 16);
}

// Q pre-scale: 1/sqrt(H) * log2(e)  (attn softmax runs in exp2 domain)
#define QSCALE (0.125f * 1.44269504f)

// ---------------- Phase 0: W -> fragment-major swizzled W^T (bf16) ----------
// wf layout: [c(32 k-chunks)][m(3)][n(4 h-tiles)][lane(64)][j(8)]
// element = W_m[k = c*32 + (lane>>4)*8 + j][h = n*16 + (lane&15)]
__global__ __launch_bounds__(256)
void wprep_kernel(const float* __restrict__ Wq,
                  const float* __restrict__ Wk,
                  const float* __restrict__ Wv,
                  unsigned short* __restrict__ wf)
{
    const int c = blockIdx.x / 3;
    const int m = blockIdx.x % 3;
    const float* W = (m == 0) ? Wq : (m == 1 ? Wk : Wv);
    const float scale = (m == 0) ? QSCALE : 1.0f;

    const int n    = threadIdx.x >> 6;
    const int lane = threadIdx.x & 63;
    const int quad = lane >> 4;
    const int col  = lane & 15;
    const int h    = n * 16 + col;

    unsigned short tmp[8];
#pragma unroll
    for (int j = 0; j < 8; ++j)
        tmp[j] = f2bfu(W[(c * 32 + quad * 8 + j) * H_ + h] * scale);
    *(uint4*)&wf[(((c * 3 + m) * 4 + n) * 64 + lane) * 8] = *(uint4*)tmp;
}

// ---------------- Phase 1: QKV projection (barrier-free) ----------------
// Block = 16 tokens, 4 independent waves; wave w owns h-tile w for all 3 mats.
// A-fragment read directly from x (L1-shared among the 4 waves), 1-chunk
// register prefetch; B-fragments are coalesced 1KB wf loads (L2-hot).
__global__ __launch_bounds__(256, 4)
void qkv_kernel(const float* __restrict__ x,
                const unsigned short* __restrict__ wf,
                unsigned short* __restrict__ qb,
                unsigned short* __restrict__ kb,
                unsigned short* __restrict__ vtb)
{
    const int tid  = threadIdx.x;
    const int wave = tid >> 6;
    const int lane = tid & 63;
    const int quad = lane >> 4;
    const int col  = lane & 15;
    const long r0  = (long)blockIdx.x * 16;

    f32x4 acc[3];
#pragma unroll
    for (int m = 0; m < 3; ++m) acc[m] = (f32x4){0.f, 0.f, 0.f, 0.f};

    // A row = col (token), k-offset = quad*8 within each 32-k chunk
    const float* xb = x + (r0 + col) * E_ + quad * 8;

    float4 a0 = *(const float4*)xb;
    float4 a1 = *(const float4*)(xb + 4);

#pragma unroll 4
    for (int c = 0; c < 32; ++c) {
        float4 n0 = a0, n1 = a1;
        if (c + 1 < 32) {
            n0 = *(const float4*)(xb + (c + 1) * 32);
            n1 = *(const float4*)(xb + (c + 1) * 32 + 4);
        }
        unsigned pk[4];
        pk[0] = f2bfu(a0.x) | ((unsigned)f2bfu(a0.y) << 16);
        pk[1] = f2bfu(a0.z) | ((unsigned)f2bfu(a0.w) << 16);
        pk[2] = f2bfu(a1.x) | ((unsigned)f2bfu(a1.y) << 16);
        pk[3] = f2bfu(a1.z) | ((unsigned)f2bfu(a1.w) << 16);
        bf16x8 af = *(bf16x8*)pk;
#pragma unroll
        for (int m = 0; m < 3; ++m) {
            bf16x8 bfg = *(const bf16x8*)&wf[(((c * 3 + m) * 4 + wave) * 64 + lane) * 8];
            acc[m] = __builtin_amdgcn_mfma_f32_16x16x32_bf16(af, bfg, acc[m], 0, 0, 0);
        }
        a0 = n0; a1 = n1;
    }

    // epilogue: D layout col=lane&15 (h-local), row=quad*4+reg (token)
    const int bidx = (int)(r0 >> 11);
    const int h    = wave * 16 + col;
#pragma unroll
    for (int r = 0; r < 4; ++r) {
        long t = r0 + quad * 4 + r;
        qb[t * H_ + h] = f2bfu(acc[0][r]);        // scale folded into Wq
        kb[t * H_ + h] = f2bfu(acc[1][r]);
        vtb[((long)(bidx * H_ + h)) * T_ + (t & (T_ - 1))] = f2bfu(acc[2][r]);
    }
}

// ---------------- Phase 2: split-K flash attention ----------------
// Block = (batch, pair p): q-tiles p and 127-p (16 rows each), sequential.
// 8 waves = 8 split-K groups; wave g handles key-tiles s = g, g+8, ...
// Q/K/V fragments read directly from global (L2-resident); LDS only for
// per-wave P transpose and the split-K combine. No barriers in the K-loop.
#define PSS 72   // P scratch row stride (shorts); col*144B is 16B-aligned

__global__ __launch_bounds__(512, 4)
void attn_kernel(const unsigned short* __restrict__ qb,
                 const unsigned short* __restrict__ kb,
                 const unsigned short* __restrict__ vtb,
                 float* __restrict__ out)
{
    __shared__ unsigned short ps[8][16 * PSS];   // 18.4 KB
    __shared__ float oc[8][16][68];              // 34.8 KB
    __shared__ float ml[8][2][16];               // 1 KB

    const int tid  = threadIdx.x;
    const int g    = tid >> 6;        // wave = split-K group
    const int lane = tid & 63;
    const int quad = lane >> 4;
    const int col  = lane & 15;
    const int b    = blockIdx.x & 7;  // batch -> XCD pinning
    const int p    = blockIdx.x >> 3; // 0..63

    const unsigned short* qbb = qb  + (long)b * T_ * H_;
    const unsigned short* kbb = kb  + (long)b * T_ * H_;
    const unsigned short* vbb = vtb + (long)b * H_ * T_;

    for (int half = 0; half < 2; ++half) {
        const int qt = half ? (127 - p) : p;          // 16-row q-tile index
        const int nt = (qt + 4) >> 2;                 // ceil((qt+1)/4) key tiles

        bf16x8 qa0 = *(const bf16x8*)&qbb[(qt * 16 + col) * H_ + quad * 8];
        bf16x8 qa1 = *(const bf16x8*)&qbb[(qt * 16 + col) * H_ + 32 + quad * 8];

        f32x4 o[4];
        float m_i[4], l_i[4];
#pragma unroll
        for (int n = 0; n < 4; ++n) o[n] = (f32x4){0.f, 0.f, 0.f, 0.f};
#pragma unroll
        for (int r = 0; r < 4; ++r) { m_i[r] = -1e30f; l_i[r] = 0.f; }

        for (int s = g; s < nt; s += 8) {
            // S = Q K^T : K fragments direct from global (L2-hot)
            f32x4 sa[4];
#pragma unroll
            for (int kt = 0; kt < 4; ++kt) {
                const unsigned short* kp = kbb + ((long)(s * 64 + kt * 16 + col)) * H_ + quad * 8;
                bf16x8 kf0 = *(const bf16x8*)kp;
                bf16x8 kf1 = *(const bf16x8*)(kp + 32);
                sa[kt] = (f32x4){0.f, 0.f, 0.f, 0.f};
                sa[kt] = __builtin_amdgcn_mfma_f32_16x16x32_bf16(qa0, kf0, sa[kt], 0, 0, 0);
                sa[kt] = __builtin_amdgcn_mfma_f32_16x16x32_bf16(qa1, kf1, sa[kt], 0, 0, 0);
            }

            if (s == nt - 1) {            // diagonal tile: causal mask
#pragma unroll
                for (int kt = 0; kt < 4; ++kt) {
                    int kg = s * 64 + kt * 16 + col;
#pragma unroll
                    for (int r = 0; r < 4; ++r) {
                        int qg = qt * 16 + quad * 4 + r;
                        if (kg > qg) sa[kt][r] = -1e30f;
                    }
                }
            }

            // online softmax (exp2 domain; scale folded into Wq)
            float mx[4];
#pragma unroll
            for (int r = 0; r < 4; ++r)
                mx[r] = fmaxf(fmaxf(sa[0][r], sa[1][r]), fmaxf(sa[2][r], sa[3][r]));
#pragma unroll
            for (int off = 1; off < 16; off <<= 1)
#pragma unroll
                for (int r = 0; r < 4; ++r)
                    mx[r] = fmaxf(mx[r], __shfl_xor(mx[r], off, 64));

            float alpha[4], mnew[4];
#pragma unroll
            for (int r = 0; r < 4; ++r) {
                mnew[r]  = fmaxf(m_i[r], mx[r]);
                alpha[r] = __builtin_amdgcn_exp2f(m_i[r] - mnew[r]);
                m_i[r]   = mnew[r];
            }

            float rs[4] = {0.f, 0.f, 0.f, 0.f};
#pragma unroll
            for (int kt = 0; kt < 4; ++kt)
#pragma unroll
                for (int r = 0; r < 4; ++r) {
                    float pv = __builtin_amdgcn_exp2f(sa[kt][r] - mnew[r]);
                    rs[r] += pv;
                    ps[g][(quad * 4 + r) * PSS + kt * 16 + col] = f2bfu(pv);
                }
#pragma unroll
            for (int off = 1; off < 16; off <<= 1)
#pragma unroll
                for (int r = 0; r < 4; ++r)
                    rs[r] += __shfl_xor(rs[r], off, 64);
#pragma unroll
            for (int r = 0; r < 4; ++r)
                l_i[r] = l_i[r] * alpha[r] + rs[r];

#pragma unroll
            for (int n = 0; n < 4; ++n)
#pragma unroll
                for (int r = 0; r < 4; ++r)
                    o[n][r] *= alpha[r];

            // O += P @ V : P from per-wave LDS (A-layout), V direct from global
            bf16x8 pa0 = *(const bf16x8*)&ps[g][col * PSS + quad * 8];
            bf16x8 pa1 = *(const bf16x8*)&ps[g][col * PSS + 32 + quad * 8];
#pragma unroll
            for (int n = 0; n < 4; ++n) {
                const unsigned short* vp = vbb + ((long)(n * 16 + col)) * T_ + s * 64 + quad * 8;
                bf16x8 vf0 = *(const bf16x8*)vp;
                bf16x8 vf1 = *(const bf16x8*)(vp + 32);
                o[n] = __builtin_amdgcn_mfma_f32_16x16x32_bf16(pa0, vf0, o[n], 0, 0, 0);
                o[n] = __builtin_amdgcn_mfma_f32_16x16x32_bf16(pa1, vf1, o[n], 0, 0, 0);
            }
        }

        // ---- split-K combine ----
#pragma unroll
        for (int r = 0; r < 4; ++r) {
            int row = quad * 4 + r;
#pragma unroll
            for (int n = 0; n < 4; ++n)
                oc[g][row][n * 16 + col] = o[n][r];
        }
        if (col == 0) {
#pragma unroll
            for (int r = 0; r < 4; ++r) {
                ml[g][0][quad * 4 + r] = m_i[r];
                ml[g][1][quad * 4 + r] = l_i[r];
            }
        }
        __syncthreads();

        // merge: wave g owns q-rows 2g, 2g+1; lane = h (0..63)
#pragma unroll
        for (int rr = 0; rr < 2; ++rr) {
            int row = g * 2 + rr;
            float M = ml[0][0][row];
#pragma unroll
            for (int j = 1; j < 8; ++j) M = fmaxf(M, ml[j][0][row]);
            float lsum = 0.f, osum = 0.f;
#pragma unroll
            for (int j = 0; j < 8; ++j) {
                float wgt = __builtin_amdgcn_exp2f(ml[j][0][row] - M);
                lsum += ml[j][1][row] * wgt;
                osum += oc[j][row][lane] * wgt;
            }
            out[((long)b * T_ + qt * 16 + row) * H_ + lane] = osum / lsum;
        }
        __syncthreads();   // before next half reuses ps/oc/ml
    }
}

extern "C" void kernel_launch(void* const* d_in, const int* in_sizes, int n_in,
                              void* d_out, int out_size, void* d_ws, size_t ws_size,
                              hipStream_t stream) {
    (void)in_sizes; (void)n_in; (void)out_size; (void)ws_size;
    const float* x  = (const float*)d_in[0];
    const float* Wq = (const float*)d_in[1];
    const float* Wk = (const float*)d_in[2];
    const float* Wv = (const float*)d_in[3];

    unsigned short* qb  = (unsigned short*)d_ws;               // 2 MB
    unsigned short* kb  = qb + (size_t)BT_ * H_;               // 2 MB
    unsigned short* vtb = kb + (size_t)BT_ * H_;               // 2 MB
    unsigned short* wf  = vtb + (size_t)BT_ * H_;              // 384 KB

    wprep_kernel<<<96, 256, 0, stream>>>(Wq, Wk, Wv, wf);
    qkv_kernel<<<BT_ / 16, 256, 0, stream>>>(x, wf, qb, kb, vtb);
    attn_kernel<<<B_ * 64, 512, 0, stream>>>(qb, kb, vtb, (float*)d_out);
}

// Round 5
// 170.069 us; speedup vs baseline: 1.4434x; 1.0050x over previous
//
#include <hip/hip_runtime.h>
#include <hip/hip_bf16.h>

#define B_  8
#define T_  2048
#define E_  1024
#define H_  64
#define BT_ (B_*T_)

typedef __attribute__((ext_vector_type(8))) __bf16 bf16x8;
typedef __attribute__((ext_vector_type(4))) float  f32x4;

__device__ __forceinline__ unsigned short f2bfu(float f) {
    union { float f; unsigned u; } v; v.f = f;
    unsigned r = v.u + 0x7fffu + ((v.u >> 16) & 1u);
    return (unsigned short)(r >> 16);
}

__device__ __forceinline__ unsigned pk2(float lo, float hi) {
    __hip_bfloat162 h = __float22bfloat162_rn(float2{lo, hi});
    union { __hip_bfloat162 h; unsigned u; } v; v.h = h;
    return v.u;
}

// Q pre-scale: 1/sqrt(H) * log2(e)  (attn softmax runs in exp2 domain)
#define QSCALE (0.125f * 1.44269504f)

// ---------------- Phase 0: W -> fragment-major swizzled W^T (bf16) ----------
// wf layout: [c(32 k-chunks)][m(3)][n(4 h-tiles)][lane(64)][j(8)]
__global__ __launch_bounds__(256)
void wprep_kernel(const float* __restrict__ Wq,
                  const float* __restrict__ Wk,
                  const float* __restrict__ Wv,
                  unsigned short* __restrict__ wf)
{
    const int c = blockIdx.x / 3;
    const int m = blockIdx.x % 3;
    const float* W = (m == 0) ? Wq : (m == 1 ? Wk : Wv);
    const float scale = (m == 0) ? QSCALE : 1.0f;

    const int n    = threadIdx.x >> 6;
    const int lane = threadIdx.x & 63;
    const int quad = lane >> 4;
    const int col  = lane & 15;
    const int h    = n * 16 + col;

    unsigned short tmp[8];
#pragma unroll
    for (int j = 0; j < 8; ++j)
        tmp[j] = f2bfu(W[(c * 32 + quad * 8 + j) * H_ + h] * scale);
    *(uint4*)&wf[(((c * 3 + m) * 4 + n) * 64 + lane) * 8] = *(uint4*)tmp;
}

// ---------------- Phase 1: QKV projection (deep register pipeline) ----------
// Block = 16 tokens, 4 independent waves; wave w owns h-tile w for all 3 mats.
// x: distance-4 prefetch ring (HBM latency ~900cyc); wf: distance-2 ring (L2).
__global__ __launch_bounds__(256, 4)
void qkv_kernel(const float* __restrict__ x,
                const unsigned short* __restrict__ wf,
                unsigned short* __restrict__ qb,
                unsigned short* __restrict__ kb,
                unsigned short* __restrict__ vtb)
{
    const int tid  = threadIdx.x;
    const int wave = tid >> 6;
    const int lane = tid & 63;
    const int quad = lane >> 4;
    const int col  = lane & 15;
    const long r0  = (long)blockIdx.x * 16;

    f32x4 acc[3];
#pragma unroll
    for (int m = 0; m < 3; ++m) acc[m] = (f32x4){0.f, 0.f, 0.f, 0.f};

    // A row = col (token), k-offset = quad*8 within each 32-k chunk
    const float* xb = x + (r0 + col) * E_ + quad * 8;

    float4 ax[4][2];
#pragma unroll
    for (int d = 0; d < 4; ++d) {
        ax[d][0] = *(const float4*)(xb + d * 32);
        ax[d][1] = *(const float4*)(xb + d * 32 + 4);
    }
    bf16x8 bw[2][3];
#pragma unroll
    for (int d = 0; d < 2; ++d)
#pragma unroll
        for (int m = 0; m < 3; ++m)
            bw[d][m] = *(const bf16x8*)&wf[(((d * 3 + m) * 4 + wave) * 64 + lane) * 8];

    for (int c = 0; c < 32; ++c) {
        float4 a0 = ax[c & 3][0], a1 = ax[c & 3][1];
        bf16x8 b0 = bw[c & 1][0], b1 = bw[c & 1][1], b2 = bw[c & 1][2];

        if (c + 4 < 32) {
            ax[c & 3][0] = *(const float4*)(xb + (c + 4) * 32);
            ax[c & 3][1] = *(const float4*)(xb + (c + 4) * 32 + 4);
        }
        if (c + 2 < 32) {
#pragma unroll
            for (int m = 0; m < 3; ++m)
                bw[c & 1][m] = *(const bf16x8*)&wf[((((c + 2) * 3 + m) * 4 + wave) * 64 + lane) * 8];
        }

        unsigned pk[4];
        pk[0] = pk2(a0.x, a0.y);
        pk[1] = pk2(a0.z, a0.w);
        pk[2] = pk2(a1.x, a1.y);
        pk[3] = pk2(a1.z, a1.w);
        bf16x8 af = *(bf16x8*)pk;

        acc[0] = __builtin_amdgcn_mfma_f32_16x16x32_bf16(af, b0, acc[0], 0, 0, 0);
        acc[1] = __builtin_amdgcn_mfma_f32_16x16x32_bf16(af, b1, acc[1], 0, 0, 0);
        acc[2] = __builtin_amdgcn_mfma_f32_16x16x32_bf16(af, b2, acc[2], 0, 0, 0);
    }

    // epilogue: D layout col=lane&15 (h-local), row=quad*4+reg (token)
    const int bidx = (int)(r0 >> 11);
    const int h    = wave * 16 + col;
#pragma unroll
    for (int r = 0; r < 4; ++r) {
        long t = r0 + quad * 4 + r;
        qb[t * H_ + h] = f2bfu(acc[0][r]);        // scale folded into Wq
        kb[t * H_ + h] = f2bfu(acc[1][r]);
        vtb[((long)(bidx * H_ + h)) * T_ + (t & (T_ - 1))] = f2bfu(acc[2][r]);
    }
}

// ---------------- Phase 2: split-K flash attention ----------------
// Block = (batch, pair p): q-tiles p and 127-p (16 rows each), sequential.
// 8 waves = 8 split-K groups; wave g handles key-tiles s = g, g+8, ...
// K fragments register-prefetched one tile ahead; LDS overlays ps/oc.
#define PSS 72

__global__ __launch_bounds__(512, 2)
void attn_kernel(const unsigned short* __restrict__ qb,
                 const unsigned short* __restrict__ kb,
                 const unsigned short* __restrict__ vtb,
                 float* __restrict__ out)
{
    // overlay: ps (18.4 KB, K-loop) shares space with oc (34.8 KB, combine)
    __shared__ char smem[8 * 16 * 68 * 4 + 8 * 2 * 16 * 4];   // 35.8 KB
    unsigned short* ps = (unsigned short*)smem;               // [8][16*PSS]
    float* oc = (float*)smem;                                 // [8][16][68]
    float* ml = (float*)(smem + 8 * 16 * 68 * 4);             // [8][2][16]

    const int tid  = threadIdx.x;
    const int g    = tid >> 6;        // wave = split-K group
    const int lane = tid & 63;
    const int quad = lane >> 4;
    const int col  = lane & 15;
    const int b    = blockIdx.x & 7;  // batch -> XCD pinning
    const int p    = blockIdx.x >> 3; // 0..63

    const unsigned short* qbb = qb  + (long)b * T_ * H_;
    const unsigned short* kbb = kb  + (long)b * T_ * H_;
    const unsigned short* vbb = vtb + (long)b * H_ * T_;

    for (int half = 0; half < 2; ++half) {
        const int qt = half ? (127 - p) : p;          // 16-row q-tile index
        const int nt = (qt + 4) >> 2;                 // ceil((qt+1)/4) key tiles

        bf16x8 qa0 = *(const bf16x8*)&qbb[(qt * 16 + col) * H_ + quad * 8];
        bf16x8 qa1 = *(const bf16x8*)&qbb[(qt * 16 + col) * H_ + 32 + quad * 8];

        f32x4 o[4];
        float m_i[4], l_i[4];
#pragma unroll
        for (int n = 0; n < 4; ++n) o[n] = (f32x4){0.f, 0.f, 0.f, 0.f};
#pragma unroll
        for (int r = 0; r < 4; ++r) { m_i[r] = -1e30f; l_i[r] = 0.f; }

        // K fragment prefetch for first tile
        bf16x8 kf[8];
        if (g < nt) {
#pragma unroll
            for (int kt = 0; kt < 4; ++kt) {
                const unsigned short* kp = kbb + ((long)(g * 64 + kt * 16 + col)) * H_ + quad * 8;
                kf[kt * 2]     = *(const bf16x8*)kp;
                kf[kt * 2 + 1] = *(const bf16x8*)(kp + 32);
            }
        }

        for (int s = g; s < nt; s += 8) {
            // S = Q K^T from prefetched fragments
            f32x4 sa[4];
#pragma unroll
            for (int kt = 0; kt < 4; ++kt) {
                sa[kt] = (f32x4){0.f, 0.f, 0.f, 0.f};
                sa[kt] = __builtin_amdgcn_mfma_f32_16x16x32_bf16(qa0, kf[kt * 2],     sa[kt], 0, 0, 0);
                sa[kt] = __builtin_amdgcn_mfma_f32_16x16x32_bf16(qa1, kf[kt * 2 + 1], sa[kt], 0, 0, 0);
            }

            // prefetch next tile's K (overlaps softmax + PV below)
            if (s + 8 < nt) {
#pragma unroll
                for (int kt = 0; kt < 4; ++kt) {
                    const unsigned short* kp = kbb + ((long)((s + 8) * 64 + kt * 16 + col)) * H_ + quad * 8;
                    kf[kt * 2]     = *(const bf16x8*)kp;
                    kf[kt * 2 + 1] = *(const bf16x8*)(kp + 32);
                }
            }

            if (s == nt - 1) {            // diagonal tile: causal mask
#pragma unroll
                for (int kt = 0; kt < 4; ++kt) {
                    int kg = s * 64 + kt * 16 + col;
#pragma unroll
                    for (int r = 0; r < 4; ++r) {
                        int qg = qt * 16 + quad * 4 + r;
                        if (kg > qg) sa[kt][r] = -1e30f;
                    }
                }
            }

            // online softmax (exp2 domain; scale folded into Wq)
            float mx[4];
#pragma unroll
            for (int r = 0; r < 4; ++r)
                mx[r] = fmaxf(fmaxf(sa[0][r], sa[1][r]), fmaxf(sa[2][r], sa[3][r]));
#pragma unroll
            for (int off = 1; off < 16; off <<= 1)
#pragma unroll
                for (int r = 0; r < 4; ++r)
                    mx[r] = fmaxf(mx[r], __shfl_xor(mx[r], off, 64));

            float alpha[4], mnew[4];
#pragma unroll
            for (int r = 0; r < 4; ++r) {
                mnew[r]  = fmaxf(m_i[r], mx[r]);
                alpha[r] = __builtin_amdgcn_exp2f(m_i[r] - mnew[r]);
                m_i[r]   = mnew[r];
            }

            float rs[4] = {0.f, 0.f, 0.f, 0.f};
#pragma unroll
            for (int kt = 0; kt < 4; ++kt)
#pragma unroll
                for (int r = 0; r < 4; ++r) {
                    float pv = __builtin_amdgcn_exp2f(sa[kt][r] - mnew[r]);
                    rs[r] += pv;
                    ps[g * 16 * PSS + (quad * 4 + r) * PSS + kt * 16 + col] = f2bfu(pv);
                }
#pragma unroll
            for (int off = 1; off < 16; off <<= 1)
#pragma unroll
                for (int r = 0; r < 4; ++r)
                    rs[r] += __shfl_xor(rs[r], off, 64);
#pragma unroll
            for (int r = 0; r < 4; ++r)
                l_i[r] = l_i[r] * alpha[r] + rs[r];

#pragma unroll
            for (int n = 0; n < 4; ++n)
#pragma unroll
                for (int r = 0; r < 4; ++r)
                    o[n][r] *= alpha[r];

            // O += P @ V : P from per-wave LDS (A-layout), V direct from global
            bf16x8 pa0 = *(const bf16x8*)&ps[g * 16 * PSS + col * PSS + quad * 8];
            bf16x8 pa1 = *(const bf16x8*)&ps[g * 16 * PSS + col * PSS + 32 + quad * 8];
#pragma unroll
            for (int n = 0; n < 4; ++n) {
                const unsigned short* vp = vbb + ((long)(n * 16 + col)) * T_ + s * 64 + quad * 8;
                bf16x8 vf0 = *(const bf16x8*)vp;
                bf16x8 vf1 = *(const bf16x8*)(vp + 32);
                o[n] = __builtin_amdgcn_mfma_f32_16x16x32_bf16(pa0, vf0, o[n], 0, 0, 0);
                o[n] = __builtin_amdgcn_mfma_f32_16x16x32_bf16(pa1, vf1, o[n], 0, 0, 0);
            }
        }

        // ---- split-K combine (oc overlays ps -> barrier first) ----
        __syncthreads();
#pragma unroll
        for (int r = 0; r < 4; ++r) {
            int row = quad * 4 + r;
#pragma unroll
            for (int n = 0; n < 4; ++n)
                oc[(g * 16 + row) * 68 + n * 16 + col] = o[n][r];
        }
        if (col == 0) {
#pragma unroll
            for (int r = 0; r < 4; ++r) {
                ml[(g * 2 + 0) * 16 + quad * 4 + r] = m_i[r];
                ml[(g * 2 + 1) * 16 + quad * 4 + r] = l_i[r];
            }
        }
        __syncthreads();

        // merge: wave g owns q-rows 2g, 2g+1; lane = h (0..63)
#pragma unroll
        for (int rr = 0; rr < 2; ++rr) {
            int row = g * 2 + rr;
            float M = ml[0 * 32 + row];
#pragma unroll
            for (int j = 1; j < 8; ++j) M = fmaxf(M, ml[j * 32 + row]);
            float lsum = 0.f, osum = 0.f;
#pragma unroll
            for (int j = 0; j < 8; ++j) {
                float wgt = __builtin_amdgcn_exp2f(ml[j * 32 + row] - M);
                lsum += ml[j * 32 + 16 + row] * wgt;
                osum += oc[(j * 16 + row) * 68 + lane] * wgt;
            }
            out[((long)b * T_ + qt * 16 + row) * H_ + lane] = osum / lsum;
        }
        __syncthreads();   // before next half reuses ps/oc/ml
    }
}

extern "C" void kernel_launch(void* const* d_in, const int* in_sizes, int n_in,
                              void* d_out, int out_size, void* d_ws, size_t ws_size,
                              hipStream_t stream) {
    (void)in_sizes; (void)n_in; (void)out_size; (void)ws_size;
    const float* x  = (const float*)d_in[0];
    const float* Wq = (const float*)d_in[1];
    const float* Wk = (const float*)d_in[2];
    const float* Wv = (const float*)d_in[3];

    unsigned short* qb  = (unsigned short*)d_ws;               // 2 MB
    unsigned short* kb  = qb + (size_t)BT_ * H_;               // 2 MB
    unsigned short* vtb = kb + (size_t)BT_ * H_;               // 2 MB
    unsigned short* wf  = vtb + (size_t)BT_ * H_;              // 384 KB

    wprep_kernel<<<96, 256, 0, stream>>>(Wq, Wk, Wv, wf);
    qkv_kernel<<<BT_ / 16, 256, 0, stream>>>(x, wf, qb, kb, vtb);
    attn_kernel<<<B_ * 64, 512, 0, stream>>>(qb, kb, vtb, (float*)d_out);
}

// Round 7
// 159.599 us; speedup vs baseline: 1.5380x; 1.0656x over previous
//
#include <hip/hip_runtime.h>
#include <hip/hip_bf16.h>

#define B_  8
#define T_  2048
#define E_  1024
#define H_  64
#define BT_ (B_*T_)

typedef __attribute__((ext_vector_type(8))) __bf16 bf16x8;
typedef __attribute__((ext_vector_type(4))) float  f32x4;

__device__ __forceinline__ unsigned short f2bfu(float f) {
    union { float f; unsigned u; } v; v.f = f;
    unsigned r = v.u + 0x7fffu + ((v.u >> 16) & 1u);
    return (unsigned short)(r >> 16);
}

__device__ __forceinline__ unsigned pk2(float lo, float hi) {
    __hip_bfloat162 h = __float22bfloat162_rn(float2{lo, hi});
    union { __hip_bfloat162 h; unsigned u; } v; v.h = h;
    return v.u;
}

// async global->LDS DMA, 16B/lane. lds_base must be wave-uniform; HW writes
// lane i at lds_base + i*16 (m104). Generic->AS3 via uintptr (low 32 = LDS off).
#if defined(__has_builtin)
#if __has_builtin(__builtin_amdgcn_global_load_lds)
#define HAVE_GLL 1
#endif
#endif
__device__ __forceinline__ void dma16(const void* g, void* lds_base, int lane) {
#ifdef HAVE_GLL
    __builtin_amdgcn_global_load_lds(
        (const __attribute__((address_space(1))) unsigned*)(unsigned long long)g,
        (__attribute__((address_space(3))) unsigned*)(unsigned)(unsigned long long)lds_base,
        16, 0, 0);
#else
    *(uint4*)((char*)lds_base + lane * 16) = *(const uint4*)g;
#endif
}

// Q pre-scale: 1/sqrt(H) * log2(e)  (attn softmax runs in exp2 domain)
#define QSCALE (0.125f * 1.44269504f)

// wf chunk byte size: 3 mats * 4 n-tiles * 64 lanes * 16 B = 12288 B
#define WF_CHUNK_BYTES 12288

// ---------------- Phase 0: W -> fragment-major swizzled W^T (bf16) ----------
// wf layout: [c(32 k-chunks)][m(3)][n(4 h-tiles)][lane(64)][j(8)]
// chunk c is 12 KB contiguous => DMA-able straight into LDS.
__global__ __launch_bounds__(256)
void wprep_kernel(const float* __restrict__ Wq,
                  const float* __restrict__ Wk,
                  const float* __restrict__ Wv,
                  unsigned short* __restrict__ wf)
{
    const int c = blockIdx.x / 3;
    const int m = blockIdx.x % 3;
    const float* W = (m == 0) ? Wq : (m == 1 ? Wk : Wv);
    const float scale = (m == 0) ? QSCALE : 1.0f;

    const int n    = threadIdx.x >> 6;
    const int lane = threadIdx.x & 63;
    const int quad = lane >> 4;
    const int col  = lane & 15;
    const int h    = n * 16 + col;

    unsigned short tmp[8];
#pragma unroll
    for (int j = 0; j < 8; ++j)
        tmp[j] = f2bfu(W[(c * 32 + quad * 8 + j) * H_ + h] * scale);
    *(uint4*)&wf[(((c * 3 + m) * 4 + n) * 64 + lane) * 8] = *(uint4*)tmp;
}

// ---------------- Phase 1: QKV projection (LDS double-buffer + DMA) --------
// Block = 16 tokens, 4 waves; wave w owns h-tile w for all 3 matrices.
// Per 32-k chunk: wf (12 KB) DMA'd to LDS, x (16x32 fp32) cvt'd to bf16 LDS.
__global__ __launch_bounds__(256, 4)
void qkv_kernel(const float* __restrict__ x,
                const unsigned short* __restrict__ wf,
                unsigned short* __restrict__ qb,
                unsigned short* __restrict__ kb,
                unsigned short* __restrict__ vtb)
{
    __shared__ __align__(16) char           wfs[2][WF_CHUNK_BYTES];   // 24 KB
    __shared__ __align__(16) unsigned short xs[2][16 * 36];           // 2.25 KB

    const int tid  = threadIdx.x;
    const int w    = tid >> 6;
    const int lane = tid & 63;
    const int quad = lane >> 4;
    const int col  = lane & 15;
    const long r0  = (long)blockIdx.x * 16;

    f32x4 acc[3];
#pragma unroll
    for (int m = 0; m < 3; ++m) acc[m] = (f32x4){0.f, 0.f, 0.f, 0.f};

    const char* wfb = (const char*)wf;
    const int   row = tid >> 4;          // 0..15 token
    const int   kk  = (tid & 15) * 2;    // 0..30 k-pair
    const float* xp = x + (r0 + row) * E_ + kk;

    // prologue: stage chunk 0, prefetch x chunk 1
    float2 xv = *(const float2*)xp;
#pragma unroll
    for (int j = 0; j < 3; ++j)
        dma16(wfb + (w * 3 + j) * 1024 + lane * 16, &wfs[0][(w * 3 + j) * 1024], lane);
    *(unsigned*)&xs[0][row * 36 + kk] = pk2(xv.x, xv.y);
    xv = *(const float2*)(xp + 32);

    for (int c = 0; c < 32; ++c) {
        const int buf = c & 1;
        __syncthreads();                 // drains DMA(c) + x ds_write(c)

        if (c + 1 < 32) {                // DMA c+1 now: one compute-phase of slack
#pragma unroll
            for (int j = 0; j < 3; ++j)
                dma16(wfb + (long)(c + 1) * WF_CHUNK_BYTES + (w * 3 + j) * 1024 + lane * 16,
                      &wfs[buf ^ 1][(w * 3 + j) * 1024], lane);
        }

        bf16x8 af = *(const bf16x8*)&xs[buf][col * 36 + quad * 8];
#pragma unroll
        for (int m = 0; m < 3; ++m) {
            bf16x8 bm = *(const bf16x8*)&wfs[buf][m * 4096 + w * 1024 + lane * 16];
            acc[m] = __builtin_amdgcn_mfma_f32_16x16x32_bf16(af, bm, acc[m], 0, 0, 0);
        }

        if (c + 1 < 32) {
            *(unsigned*)&xs[buf ^ 1][row * 36 + kk] = pk2(xv.x, xv.y);
            if (c + 2 < 32) xv = *(const float2*)(xp + (c + 2) * 32);
        }
    }

    // epilogue: D layout col=lane&15 (h-local), row=quad*4+reg (token)
    const int bidx = (int)(r0 >> 11);
    const int h    = w * 16 + col;
#pragma unroll
    for (int r = 0; r < 4; ++r) {
        long t = r0 + quad * 4 + r;
        qb[t * H_ + h] = f2bfu(acc[0][r]);        // scale folded into Wq
        kb[t * H_ + h] = f2bfu(acc[1][r]);
        vtb[((long)(bidx * H_ + h)) * T_ + (t & (T_ - 1))] = f2bfu(acc[2][r]);
    }
}

// ---------------- Phase 2: split-K flash attention ----------------
// Block = (batch, pair p): q-tiles p and 127-p (16 rows each), sequential.
// 8 waves = 8 split-K groups; wave g handles key-tiles s = g, g+8, ...
// K prefetched one tile ahead; V hoisted above softmax (~150cyc distance).
#define PSS 72

__global__ __launch_bounds__(512, 2)
void attn_kernel(const unsigned short* __restrict__ qb,
                 const unsigned short* __restrict__ kb,
                 const unsigned short* __restrict__ vtb,
                 float* __restrict__ out)
{
    // overlay: ps (18.4 KB, K-loop) shares space with oc (34.8 KB, combine)
    __shared__ char smem[8 * 16 * 68 * 4 + 8 * 2 * 16 * 4];   // 35.8 KB
    unsigned short* ps = (unsigned short*)smem;               // [8][16*PSS]
    float* oc = (float*)smem;                                 // [8][16][68]
    float* ml = (float*)(smem + 8 * 16 * 68 * 4);             // [8][2][16]

    const int tid  = threadIdx.x;
    const int g    = tid >> 6;        // wave = split-K group
    const int lane = tid & 63;
    const int quad = lane >> 4;
    const int col  = lane & 15;
    const int b    = blockIdx.x & 7;  // batch -> XCD pinning
    const int p    = blockIdx.x >> 3; // 0..63

    const unsigned short* qbb = qb  + (long)b * T_ * H_;
    const unsigned short* kbb = kb  + (long)b * T_ * H_;
    const unsigned short* vbb = vtb + (long)b * H_ * T_;

    for (int half = 0; half < 2; ++half) {
        const int qt = half ? (127 - p) : p;          // 16-row q-tile index
        const int nt = (qt + 4) >> 2;                 // ceil((qt+1)/4) key tiles

        bf16x8 qa0 = *(const bf16x8*)&qbb[(qt * 16 + col) * H_ + quad * 8];
        bf16x8 qa1 = *(const bf16x8*)&qbb[(qt * 16 + col) * H_ + 32 + quad * 8];

        f32x4 o[4];
        float m_i[4], l_i[4];
#pragma unroll
        for (int n = 0; n < 4; ++n) o[n] = (f32x4){0.f, 0.f, 0.f, 0.f};
#pragma unroll
        for (int r = 0; r < 4; ++r) { m_i[r] = -1e30f; l_i[r] = 0.f; }

        // K fragment prefetch for first tile
        bf16x8 kf[8];
        if (g < nt) {
#pragma unroll
            for (int kt = 0; kt < 4; ++kt) {
                const unsigned short* kp = kbb + ((long)(g * 64 + kt * 16 + col)) * H_ + quad * 8;
                kf[kt * 2]     = *(const bf16x8*)kp;
                kf[kt * 2 + 1] = *(const bf16x8*)(kp + 32);
            }
        }

        for (int s = g; s < nt; s += 8) {
            // S = Q K^T from prefetched fragments
            f32x4 sa[4];
#pragma unroll
            for (int kt = 0; kt < 4; ++kt) {
                sa[kt] = (f32x4){0.f, 0.f, 0.f, 0.f};
                sa[kt] = __builtin_amdgcn_mfma_f32_16x16x32_bf16(qa0, kf[kt * 2],     sa[kt], 0, 0, 0);
                sa[kt] = __builtin_amdgcn_mfma_f32_16x16x32_bf16(qa1, kf[kt * 2 + 1], sa[kt], 0, 0, 0);
            }

            // hoist V(s) loads: ~softmax-duration ahead of the PV use
            bf16x8 vf[8];
#pragma unroll
            for (int n = 0; n < 4; ++n) {
                const unsigned short* vp = vbb + ((long)(n * 16 + col)) * T_ + s * 64 + quad * 8;
                vf[n * 2]     = *(const bf16x8*)vp;
                vf[n * 2 + 1] = *(const bf16x8*)(vp + 32);
            }

            // prefetch next tile's K (overlaps softmax + PV below)
            if (s + 8 < nt) {
#pragma unroll
                for (int kt = 0; kt < 4; ++kt) {
                    const unsigned short* kp = kbb + ((long)((s + 8) * 64 + kt * 16 + col)) * H_ + quad * 8;
                    kf[kt * 2]     = *(const bf16x8*)kp;
                    kf[kt * 2 + 1] = *(const bf16x8*)(kp + 32);
                }
            }

            if (s == nt - 1) {            // diagonal tile: causal mask
#pragma unroll
                for (int kt = 0; kt < 4; ++kt) {
                    int kg = s * 64 + kt * 16 + col;
#pragma unroll
                    for (int r = 0; r < 4; ++r) {
                        int qg = qt * 16 + quad * 4 + r;
                        if (kg > qg) sa[kt][r] = -1e30f;
                    }
                }
            }

            // online softmax (exp2 domain; scale folded into Wq)
            float mx[4];
#pragma unroll
            for (int r = 0; r < 4; ++r)
                mx[r] = fmaxf(fmaxf(sa[0][r], sa[1][r]), fmaxf(sa[2][r], sa[3][r]));
#pragma unroll
            for (int off = 1; off < 16; off <<= 1)
#pragma unroll
                for (int r = 0; r < 4; ++r)
                    mx[r] = fmaxf(mx[r], __shfl_xor(mx[r], off, 64));

            float alpha[4], mnew[4];
#pragma unroll
            for (int r = 0; r < 4; ++r) {
                mnew[r]  = fmaxf(m_i[r], mx[r]);
                alpha[r] = __builtin_amdgcn_exp2f(m_i[r] - mnew[r]);
                m_i[r]   = mnew[r];
            }

            float rs[4] = {0.f, 0.f, 0.f, 0.f};
#pragma unroll
            for (int kt = 0; kt < 4; ++kt)
#pragma unroll
                for (int r = 0; r < 4; ++r) {
                    float pv = __builtin_amdgcn_exp2f(sa[kt][r] - mnew[r]);
                    rs[r] += pv;
                    ps[g * 16 * PSS + (quad * 4 + r) * PSS + kt * 16 + col] = f2bfu(pv);
                }
#pragma unroll
            for (int off = 1; off < 16; off <<= 1)
#pragma unroll
                for (int r = 0; r < 4; ++r)
                    rs[r] += __shfl_xor(rs[r], off, 64);
#pragma unroll
            for (int r = 0; r < 4; ++r)
                l_i[r] = l_i[r] * alpha[r] + rs[r];

#pragma unroll
            for (int n = 0; n < 4; ++n)
#pragma unroll
                for (int r = 0; r < 4; ++r)
                    o[n][r] *= alpha[r];

            // O += P @ V : P from per-wave LDS (A-layout), V already in regs
            bf16x8 pa0 = *(const bf16x8*)&ps[g * 16 * PSS + col * PSS + quad * 8];
            bf16x8 pa1 = *(const bf16x8*)&ps[g * 16 * PSS + col * PSS + 32 + quad * 8];
#pragma unroll
            for (int n = 0; n < 4; ++n) {
                o[n] = __builtin_amdgcn_mfma_f32_16x16x32_bf16(pa0, vf[n * 2],     o[n], 0, 0, 0);
                o[n] = __builtin_amdgcn_mfma_f32_16x16x32_bf16(pa1, vf[n * 2 + 1], o[n], 0, 0, 0);
            }
        }

        // ---- split-K combine (oc overlays ps -> barrier first) ----
        __syncthreads();
#pragma unroll
        for (int r = 0; r < 4; ++r) {
            int row = quad * 4 + r;
#pragma unroll
            for (int n = 0; n < 4; ++n)
                oc[(g * 16 + row) * 68 + n * 16 + col] = o[n][r];
        }
        if (col == 0) {
#pragma unroll
            for (int r = 0; r < 4; ++r) {
                ml[(g * 2 + 0) * 16 + quad * 4 + r] = m_i[r];
                ml[(g * 2 + 1) * 16 + quad * 4 + r] = l_i[r];
            }
        }
        __syncthreads();

        // merge: wave g owns q-rows 2g, 2g+1; lane = h (0..63)
#pragma unroll
        for (int rr = 0; rr < 2; ++rr) {
            int row = g * 2 + rr;
            float M = ml[0 * 32 + row];
#pragma unroll
            for (int j = 1; j < 8; ++j) M = fmaxf(M, ml[j * 32 + row]);
            float lsum = 0.f, osum = 0.f;
#pragma unroll
            for (int j = 0; j < 8; ++j) {
                float wgt = __builtin_amdgcn_exp2f(ml[j * 32 + row] - M);
                lsum += ml[j * 32 + 16 + row] * wgt;
                osum += oc[(j * 16 + row) * 68 + lane] * wgt;
            }
            out[((long)b * T_ + qt * 16 + row) * H_ + lane] = osum / lsum;
        }
        __syncthreads();   // before next half reuses ps/oc/ml
    }
}

extern "C" void kernel_launch(void* const* d_in, const int* in_sizes, int n_in,
                              void* d_out, int out_size, void* d_ws, size_t ws_size,
                              hipStream_t stream) {
    (void)in_sizes; (void)n_in; (void)out_size; (void)ws_size;
    const float* x  = (const float*)d_in[0];
    const float* Wq = (const float*)d_in[1];
    const float* Wk = (const float*)d_in[2];
    const float* Wv = (const float*)d_in[3];

    unsigned short* qb  = (unsigned short*)d_ws;               // 2 MB
    unsigned short* kb  = qb + (size_t)BT_ * H_;               // 2 MB
    unsigned short* vtb = kb + (size_t)BT_ * H_;               // 2 MB
    unsigned short* wf  = vtb + (size_t)BT_ * H_;              // 384 KB

    wprep_kernel<<<96, 256, 0, stream>>>(Wq, Wk, Wv, wf);
    qkv_kernel<<<BT_ / 16, 256, 0, stream>>>(x, wf, qb, kb, vtb);
    attn_kernel<<<B_ * 64, 512, 0, stream>>>(qb, kb, vtb, (float*)d_out);
}